// Round 9
// baseline (228.477 us; speedup 1.0000x reference)
//
#include <hip/hip_runtime.h>

#define S 2048
#define D 128
#define BATCH 8
#define NS 4       // key-split factor
#define KSTR 136   // K LDS row stride (halves)
#define VSTR 72    // V^T LDS row stride (halves)
#define GRID 512

typedef _Float16 half8 __attribute__((ext_vector_type(8)));
typedef _Float16 half4_t __attribute__((ext_vector_type(4)));
typedef float f4 __attribute__((ext_vector_type(4)));

__device__ __forceinline__ half8 cvt8(f4 a, f4 b) {
    half8 h;
    h[0] = (_Float16)a[0]; h[1] = (_Float16)a[1];
    h[2] = (_Float16)a[2]; h[3] = (_Float16)a[3];
    h[4] = (_Float16)b[0]; h[5] = (_Float16)b[1];
    h[6] = (_Float16)b[2]; h[7] = (_Float16)b[3];
    return h;
}

// Software grid barrier: all GRID blocks are co-resident by construction
// (launch_bounds(256,2) => VGPR<=256; LDS 35840B => 2 blocks/CU by both
// limits => 512 slots on 256 CUs). Counters zeroed by a memset node.
__device__ __forceinline__ void gridbar(unsigned* ctr) {
    __syncthreads();
    if (threadIdx.x == 0) {
        __threadfence();  // make this block's writes device-visible
        __hip_atomic_fetch_add(ctr, 1u, __ATOMIC_ACQ_REL, __HIP_MEMORY_SCOPE_AGENT);
        while (__hip_atomic_load(ctr, __ATOMIC_ACQUIRE, __HIP_MEMORY_SCOPE_AGENT) < GRID)
            __builtin_amdgcn_s_sleep(8);
    }
    __syncthreads();
}

// One kernel: phase1 prep -> bar -> phase2 attn -> bar -> phase3 combine.
__global__ __launch_bounds__(256, 2) void k_fused(
    const float* __restrict__ q, const float* __restrict__ kin,
    const float* __restrict__ v, const int* __restrict__ el,
    float* __restrict__ out, _Float16* __restrict__ kh,
    _Float16* __restrict__ vt, float* __restrict__ psums,
    float* __restrict__ stats, _Float16* __restrict__ part,
    unsigned* __restrict__ bar) {
    __shared__ alignas(16) char smem[35840];
    int tid = threadIdx.x;

    // ================= phase 1: K cast fp16, V transpose, V col-sums ========
    {
        int ch = blockIdx.x;            // 512 chunks of 32 rows
        int b = ch >> 6, c = ch & 63;
        size_t off = ((size_t)b * S + c * 32) * D;
        #pragma unroll
        for (int p = 0; p < 2; ++p) {   // K cast: 32x128 elems
            size_t i = (size_t)p * 2048 + tid * 8;
            f4 a = *(const f4*)(kin + off + i);
            f4 bb = *(const f4*)(kin + off + i + 4);
            *(half8*)(kh + off + i) = cvt8(a, bb);
        }
        float* tile = (float*)smem;             // 32 x 132 fp32
        f4* sred = (f4*)(smem + 16896);         // 256 x 2 f4
        f4 a0 = {0.f, 0.f, 0.f, 0.f}, a1 = {0.f, 0.f, 0.f, 0.f};
        int d0 = (tid & 15) * 8, rt = tid >> 4;
        #pragma unroll
        for (int p = 0; p < 2; ++p) {
            int t = p * 16 + rt;
            f4 x = *(const f4*)(v + off + (size_t)t * D + d0);
            f4 y = *(const f4*)(v + off + (size_t)t * D + d0 + 4);
            a0 += x; a1 += y;
            *(f4*)&tile[t * 132 + d0] = x;
            *(f4*)&tile[t * 132 + d0 + 4] = y;
        }
        sred[tid * 2] = a0; sred[tid * 2 + 1] = a1;
        __syncthreads();
        if (tid < 16) {   // per-chunk column partial sums (no atomics)
            f4 s0 = sred[tid * 2], s1 = sred[tid * 2 + 1];
            for (int g = 1; g < 16; ++g) {
                s0 += sred[(g * 16 + tid) * 2];
                s1 += sred[(g * 16 + tid) * 2 + 1];
            }
            *(f4*)(psums + ch * 128 + tid * 8) = s0;
            *(f4*)(psums + ch * 128 + tid * 8 + 4) = s1;
        }
        int u = tid & 3, dd = tid >> 2;
        #pragma unroll
        for (int pass = 0; pass < 2; ++pass) {
            int d = pass * 64 + dd;
            half8 h;
            #pragma unroll
            for (int i = 0; i < 8; ++i) h[i] = (_Float16)tile[(u * 8 + i) * 132 + d];
            *(half8*)(vt + ((size_t)(b * D + d)) * S + c * 32 + u * 8) = h;
        }
    }
    gridbar(bar);

    // ================= phase 2: flash attention (R7 body, grid-stride) ======
    {
        int nm[BATCH], T = 0;
        #pragma unroll
        for (int bb = 0; bb < BATCH; ++bb) {
            int c = ((el[bb] + 63) >> 6) * NS;
            nm[bb] = c; T += c;
        }
        _Float16* Kh = (_Float16*)smem;
        _Float16* Vt = (_Float16*)(smem + 64 * KSTR * 2);
        int lane = tid & 63, w = tid >> 6;
        int col = lane & 15, quad = lane >> 4;
        int kr = tid >> 4, kc8 = (tid & 15) << 3;
        int vr = tid >> 3, vc8 = (tid & 7) << 3;
        const float scale = 0.0883883476483184f;   // 1/sqrt(128)

        for (int it = blockIdx.x; it < T; it += GRID) {
            int rel = it, b = 0;
            while (rel >= nm[b]) { rel -= nm[b]; ++b; }
            int mg = rel >> 2, j = rel & 3;
            int Lb = el[b], m0 = mg * 64;
            int nkt = (Lb + 63) >> 6;
            __syncthreads();   // LDS handoff between items / from phase 1

            half8 qf[4];
            {
                const float* qb = q + ((size_t)b * S + m0 + w * 16 + col) * D;
                #pragma unroll
                for (int kc = 0; kc < 4; ++kc) {
                    f4 a = *(const f4*)(qb + kc * 32 + quad * 8);
                    f4 b2 = *(const f4*)(qb + kc * 32 + quad * 8 + 4);
                    a *= scale; b2 *= scale;
                    qf[kc] = cvt8(a, b2);
                }
            }
            f4 O[8];
            #pragma unroll
            for (int i = 0; i < 8; ++i) O[i] = (f4){0.f, 0.f, 0.f, 0.f};
            float ps = 0.f;
            const _Float16* kb_ = kh + (size_t)b * S * D;
            const _Float16* vb_ = vt + (size_t)b * D * S;

            if (j < nkt) {
                half8 kreg[4], vreg[4];
                {
                    int t0 = j * 64;
                    #pragma unroll
                    for (int p = 0; p < 4; ++p)
                        kreg[p] = *(const half8*)(kb_ + (size_t)(t0 + p * 16 + kr) * D + kc8);
                    #pragma unroll
                    for (int p = 0; p < 4; ++p)
                        vreg[p] = *(const half8*)(vb_ + (size_t)(p * 32 + vr) * S + t0 + vc8);
                    #pragma unroll
                    for (int p = 0; p < 4; ++p)
                        *(half8*)&Kh[(p * 16 + kr) * KSTR + kc8] = kreg[p];
                    #pragma unroll
                    for (int p = 0; p < 4; ++p)
                        *(half8*)&Vt[(p * 32 + vr) * VSTR + vc8] = vreg[p];
                }
                __syncthreads();

                for (int kt = j; kt < nkt; kt += NS) {
                    int t0 = kt * 64;
                    bool hasnext = (kt + NS) < nkt;
                    if (hasnext) {   // register prefetch of the next tile
                        int tn = t0 + NS * 64;
                        #pragma unroll
                        for (int p = 0; p < 4; ++p)
                            kreg[p] = *(const half8*)(kb_ + (size_t)(tn + p * 16 + kr) * D + kc8);
                        #pragma unroll
                        for (int p = 0; p < 4; ++p)
                            vreg[p] = *(const half8*)(vb_ + (size_t)(p * 32 + vr) * S + tn + vc8);
                    }
                    #pragma unroll
                    for (int nt = 0; nt < 4; ++nt) {
                        // S^T = K Q^T: C[key = nt*16+quad*4+r][qrow = col]
                        f4 sa = {0.f, 0.f, 0.f, 0.f};
                        #pragma unroll
                        for (int kc = 0; kc < 4; ++kc) {
                            half8 kf = *(const half8*)&Kh[(nt * 16 + col) * KSTR + kc * 32 + quad * 8];
                            sa = __builtin_amdgcn_mfma_f32_16x16x32_f16(kf, qf[kc], sa, 0, 0, 0);
                        }
                        int tq = t0 + nt * 16 + quad * 4;
                        half4_t ph;
                        #pragma unroll
                        for (int r = 0; r < 4; ++r) {
                            float e = (tq + r < Lb) ? __expf(fminf(sa[r], 10.0f)) : 0.f;
                            ps += e;
                            ph[r] = (_Float16)e;
                        }
                        #pragma unroll
                        for (int dt = 0; dt < 8; ++dt) {
                            half4_t vf = *(const half4_t*)&Vt[(dt * 16 + col) * VSTR + nt * 16 + quad * 4];
                            O[dt] = __builtin_amdgcn_mfma_f32_16x16x16f16(ph, vf, O[dt], 0, 0, 0);
                        }
                    }
                    if (hasnext) {
                        __syncthreads();
                        #pragma unroll
                        for (int p = 0; p < 4; ++p)
                            *(half8*)&Kh[(p * 16 + kr) * KSTR + kc8] = kreg[p];
                        #pragma unroll
                        for (int p = 0; p < 4; ++p)
                            *(half8*)&Vt[(p * 32 + vr) * VSTR + vc8] = vreg[p];
                        __syncthreads();
                    }
                }
            }

            // epilogue: l-reduce over quads, write fp16 partials + stats
            ps += __shfl_xor(ps, 16, 64);
            ps += __shfl_xor(ps, 32, 64);
            size_t pbase = (size_t)(j * BATCH + b) * S;
            #pragma unroll
            for (int dt = 0; dt < 8; ++dt)
                #pragma unroll
                for (int r = 0; r < 4; ++r) {
                    int row = m0 + w * 16 + quad * 4 + r;
                    part[(pbase + row) * D + dt * 16 + col] = (_Float16)O[dt][r];
                }
            if (quad == 0) stats[pbase + m0 + w * 16 + col] = ps;
        }
    }
    gridbar(bar + 32);

    // ================= phase 3: combine splits, normalize, masked mean ======
    {
        int ch = blockIdx.x;            // 512 chunks of 32 rows
        int b = ch >> 6, c2 = ch & 63;
        int L = el[b], m0 = c2 * 32;
        float* cmean = (float*)smem;    // 128 floats
        bool needMean = (m0 + 31) >= L; // block-uniform
        if (needMean) {
            __syncthreads();            // smem was phase-2 LDS
            if (tid < 128) {
                float cs = 0.f;
                for (int cc = 0; cc < 64; ++cc)
                    cs += psums[(b * 64 + cc) * 128 + tid];
                cmean[tid] = cs * (1.0f / (float)S);
            }
            __syncthreads();
        }
        int r = tid >> 3, d0 = (tid & 7) * 16;
        int srow = m0 + r;
        float* orow = out + ((size_t)b * S + srow) * D + d0;
        if (srow >= L) {
            #pragma unroll
            for (int sg = 0; sg < 4; ++sg)
                *(f4*)(orow + sg * 4) = *(const f4*)&cmean[d0 + sg * 4];
        } else {
            size_t rbase = (size_t)b * S + srow;
            const size_t step = (size_t)BATCH * S;
            float l = 0.f;
            #pragma unroll
            for (int jj = 0; jj < NS; ++jj) l += stats[rbase + jj * step];
            float inv = 1.0f / l;
            f4 o[4];
            #pragma unroll
            for (int i = 0; i < 4; ++i) o[i] = (f4){0.f, 0.f, 0.f, 0.f};
            #pragma unroll
            for (int jj = 0; jj < NS; ++jj) {
                const half8* p = (const half8*)(part + (rbase + jj * step) * D + d0);
                #pragma unroll
                for (int sg = 0; sg < 2; ++sg) {
                    half8 h = p[sg];
                    f4 x0 = {(float)h[0], (float)h[1], (float)h[2], (float)h[3]};
                    f4 x1 = {(float)h[4], (float)h[5], (float)h[6], (float)h[7]};
                    o[sg * 2] += x0;
                    o[sg * 2 + 1] += x1;
                }
            }
            #pragma unroll
            for (int i = 0; i < 4; ++i) *(f4*)(orow + i * 4) = o[i] * inv;
        }
    }
}

extern "C" void kernel_launch(void* const* d_in, const int* in_sizes, int n_in,
                              void* d_out, int out_size, void* d_ws, size_t ws_size,
                              hipStream_t stream) {
    const float* q = (const float*)d_in[0];
    const float* k = (const float*)d_in[1];
    const float* v = (const float*)d_in[2];
    const int* el = (const int*)d_in[3];
    float* out = (float*)d_out;

    // ws layout: bar(256B) | kh | vt | psums | stats | part
    const size_t SZ_BAR = 256;
    const size_t SZ_HALF = (size_t)BATCH * D * S * 2;     // 4.19 MB each
    const size_t SZ_PS = (size_t)GRID * 128 * 4;          // 256 KB
    const size_t SZ_STAT = (size_t)NS * BATCH * S * 4;    // 256 KB
    unsigned* bar = (unsigned*)d_ws;
    _Float16* kh = (_Float16*)((char*)d_ws + SZ_BAR);
    _Float16* vt = (_Float16*)((char*)d_ws + SZ_BAR + SZ_HALF);
    float* psums = (float*)((char*)d_ws + SZ_BAR + 2 * SZ_HALF);
    float* stats = (float*)((char*)d_ws + SZ_BAR + 2 * SZ_HALF + SZ_PS);
    _Float16* part = (_Float16*)((char*)d_ws + SZ_BAR + 2 * SZ_HALF + SZ_PS + SZ_STAT);

    hipMemsetAsync(d_ws, 0, SZ_BAR, stream);
    k_fused<<<dim3(GRID), dim3(256), 0, stream>>>(q, k, v, el, out, kh, vt,
                                                  psums, stats, part, bar);
}

// Round 10
// 122.091 us; speedup vs baseline: 1.8714x; 1.8714x over previous
//
#include <hip/hip_runtime.h>

#define S 2048
#define D 128
#define BATCH 8
#define NS 4       // key-split factor
#define KSTR 136   // K LDS row stride (halves)
#define VSTR 72    // V^T LDS row stride (halves)

typedef _Float16 half8 __attribute__((ext_vector_type(8)));
typedef _Float16 half4_t __attribute__((ext_vector_type(4)));
typedef float f4 __attribute__((ext_vector_type(4)));

__device__ __forceinline__ half8 cvt8(f4 a, f4 b) {
    half8 h;
    h[0] = (_Float16)a[0]; h[1] = (_Float16)a[1];
    h[2] = (_Float16)a[2]; h[3] = (_Float16)a[3];
    h[4] = (_Float16)b[0]; h[5] = (_Float16)b[1];
    h[6] = (_Float16)b[2]; h[7] = (_Float16)b[3];
    return h;
}

// ---- prep: K cast fp16, V transpose -> vt[b][d][t] fp16, per-chunk V
// column sums (no atomics); block (0,0) zeroes the done[] counters. ----
__global__ __launch_bounds__(256) void k_prep(const float* __restrict__ kin,
                                              const float* __restrict__ v,
                                              _Float16* __restrict__ kh,
                                              _Float16* __restrict__ vt,
                                              float* __restrict__ psums,
                                              unsigned* __restrict__ done) {
    int b = blockIdx.y, c = blockIdx.x, tid = threadIdx.x;
    if (b == 0 && c == 0 && tid < 256) done[tid] = 0u;
    size_t off = ((size_t)b * S + c * 64) * D;
    #pragma unroll
    for (int p = 0; p < 4; ++p) {
        size_t i = (size_t)p * 2048 + tid * 8;
        f4 a = *(const f4*)(kin + off + i);
        f4 bb = *(const f4*)(kin + off + i + 4);
        *(half8*)(kh + off + i) = cvt8(a, bb);
    }
    __shared__ float tile[64 * 132];
    __shared__ f4 sred[256][2];
    f4 a0 = {0.f, 0.f, 0.f, 0.f}, a1 = {0.f, 0.f, 0.f, 0.f};
    int d0 = (tid & 15) * 8;
    #pragma unroll
    for (int p = 0; p < 4; ++p) {
        int t = p * 16 + (tid >> 4);
        f4 x = *(const f4*)(v + off + (size_t)t * D + d0);
        f4 y = *(const f4*)(v + off + (size_t)t * D + d0 + 4);
        a0 += x; a1 += y;
        *(f4*)&tile[t * 132 + d0] = x;
        *(f4*)&tile[t * 132 + d0 + 4] = y;
    }
    sred[tid][0] = a0; sred[tid][1] = a1;
    __syncthreads();
    if (tid < 16) {   // per-chunk column sums, direct store
        f4 s0 = sred[tid][0], s1 = sred[tid][1];
        for (int g = 1; g < 16; ++g) { s0 += sred[g * 16 + tid][0]; s1 += sred[g * 16 + tid][1]; }
        *(f4*)(psums + (b * 32 + c) * 128 + tid * 8) = s0;
        *(f4*)(psums + (b * 32 + c) * 128 + tid * 8 + 4) = s1;
    }
    int u = tid & 7, dd = tid >> 3;
    #pragma unroll
    for (int pass = 0; pass < 4; ++pass) {
        int d = pass * 32 + dd;
        half8 h;
        #pragma unroll
        for (int i = 0; i < 8; ++i) h[i] = (_Float16)tile[(u * 8 + i) * 132 + d];
        *(half8*)(vt + ((size_t)(b * D + d)) * S + c * 64 + u * 8) = h;
    }
}

// ---- attn: dense queue. Items [0,T): attention (b, mg, j); the 4th split
// to finish a (b, mg) group combines + writes output (last-finisher, via
// one ACQ_REL agent atomic). Items [T, T+F): mean-fill for rows >= L. ----
__global__ __launch_bounds__(256, 3) void k_attn(
    const float* __restrict__ q, const _Float16* __restrict__ kh,
    const _Float16* __restrict__ vt, const int* __restrict__ el,
    const float* __restrict__ psums, _Float16* __restrict__ part,
    float* __restrict__ stats, unsigned* __restrict__ done,
    float* __restrict__ out) {
    int nm[BATCH], fm[BATCH], T = 0, F = 0;
    #pragma unroll
    for (int bb = 0; bb < BATCH; ++bb) {
        int g = (el[bb] + 63) >> 6;
        nm[bb] = g * NS; T += g * NS;
        fm[bb] = 32 - g; F += 32 - g;
    }
    int it = blockIdx.x, tid = threadIdx.x;
    __shared__ float cmean[128];
    __shared__ int cflag;

    if (it >= T) {  // ---------- mean-fill item ----------
        if (it >= T + F) return;
        int rel = it - T, b = 0;
        while (rel >= fm[b]) { rel -= fm[b]; ++b; }
        int mg = ((el[b] + 63) >> 6) + rel;
        int m0 = mg * 64;
        if (tid < 128) {
            float cs = 0.f;
            #pragma unroll 4
            for (int cc = 0; cc < 32; ++cc) cs += psums[(b * 32 + cc) * 128 + tid];
            cmean[tid] = cs * (1.0f / (float)S);
        }
        __syncthreads();
        int d0 = (tid & 31) * 4, r0 = tid >> 5;
        f4 mv = *(const f4*)&cmean[d0];
        #pragma unroll
        for (int i = 0; i < 8; ++i) {
            int row = m0 + r0 + 8 * i;
            *(f4*)(out + ((size_t)b * S + row) * D + d0) = mv;
        }
        return;
    }

    // ---------- attention item ----------
    int rel = it, b = 0;
    while (rel >= nm[b]) { rel -= nm[b]; ++b; }
    int mg = rel >> 2, j = rel & 3;
    int Lb = el[b], m0 = mg * 64;
    int nkt = (Lb + 63) >> 6;

    int lane = tid & 63, w = tid >> 6;
    int col = lane & 15, quad = lane >> 4;

    __shared__ _Float16 Kh[64 * KSTR];
    __shared__ _Float16 Vt[128 * VSTR];

    const float scale = 0.0883883476483184f;  // 1/sqrt(128)
    half8 qf[4];
    {
        const float* qb = q + ((size_t)b * S + m0 + w * 16 + col) * D;
        #pragma unroll
        for (int kc = 0; kc < 4; ++kc) {
            f4 a = *(const f4*)(qb + kc * 32 + quad * 8);
            f4 b2 = *(const f4*)(qb + kc * 32 + quad * 8 + 4);
            a *= scale; b2 *= scale;
            qf[kc] = cvt8(a, b2);
        }
    }

    f4 O[8];
    #pragma unroll
    for (int i = 0; i < 8; ++i) O[i] = (f4){0.f, 0.f, 0.f, 0.f};
    float ps = 0.f;

    int kr = tid >> 4, kc8 = (tid & 15) << 3;
    int vr = tid >> 3, vc8 = (tid & 7) << 3;
    const _Float16* kb_ = kh + (size_t)b * S * D;
    const _Float16* vb_ = vt + (size_t)b * D * S;

    if (j < nkt) {
        half8 kreg[4], vreg[4];
        {
            int t0 = j * 64;
            #pragma unroll
            for (int p = 0; p < 4; ++p)
                kreg[p] = *(const half8*)(kb_ + (size_t)(t0 + p * 16 + kr) * D + kc8);
            #pragma unroll
            for (int p = 0; p < 4; ++p)
                vreg[p] = *(const half8*)(vb_ + (size_t)(p * 32 + vr) * S + t0 + vc8);
            #pragma unroll
            for (int p = 0; p < 4; ++p)
                *(half8*)&Kh[(p * 16 + kr) * KSTR + kc8] = kreg[p];
            #pragma unroll
            for (int p = 0; p < 4; ++p)
                *(half8*)&Vt[(p * 32 + vr) * VSTR + vc8] = vreg[p];
        }
        __syncthreads();

        for (int kt = j; kt < nkt; kt += NS) {
            int t0 = kt * 64;
            bool hasnext = (kt + NS) < nkt;
            if (hasnext) {  // register prefetch of the next tile
                int tn = t0 + NS * 64;
                #pragma unroll
                for (int p = 0; p < 4; ++p)
                    kreg[p] = *(const half8*)(kb_ + (size_t)(tn + p * 16 + kr) * D + kc8);
                #pragma unroll
                for (int p = 0; p < 4; ++p)
                    vreg[p] = *(const half8*)(vb_ + (size_t)(p * 32 + vr) * S + tn + vc8);
            }
            #pragma unroll
            for (int nt = 0; nt < 4; ++nt) {
                // S^T = K Q^T: C[key = nt*16+quad*4+r][qrow = col]
                f4 sa = {0.f, 0.f, 0.f, 0.f};
                #pragma unroll
                for (int kc = 0; kc < 4; ++kc) {
                    half8 kf = *(const half8*)&Kh[(nt * 16 + col) * KSTR + kc * 32 + quad * 8];
                    sa = __builtin_amdgcn_mfma_f32_16x16x32_f16(kf, qf[kc], sa, 0, 0, 0);
                }
                int tq = t0 + nt * 16 + quad * 4;
                half4_t ph;
                #pragma unroll
                for (int r = 0; r < 4; ++r) {
                    float e = (tq + r < Lb) ? __expf(fminf(sa[r], 10.0f)) : 0.f;
                    ps += e;
                    ph[r] = (_Float16)e;
                }
                #pragma unroll
                for (int dt = 0; dt < 8; ++dt) {
                    half4_t vf = *(const half4_t*)&Vt[(dt * 16 + col) * VSTR + nt * 16 + quad * 4];
                    O[dt] = __builtin_amdgcn_mfma_f32_16x16x16f16(ph, vf, O[dt], 0, 0, 0);
                }
            }
            if (hasnext) {
                __syncthreads();
                #pragma unroll
                for (int p = 0; p < 4; ++p)
                    *(half8*)&Kh[(p * 16 + kr) * KSTR + kc8] = kreg[p];
                #pragma unroll
                for (int p = 0; p < 4; ++p)
                    *(half8*)&Vt[(p * 32 + vr) * VSTR + vc8] = vreg[p];
                __syncthreads();
            }
        }
    }

    // epilogue: l-reduce over quads, write fp16 partials + stats
    ps += __shfl_xor(ps, 16, 64);
    ps += __shfl_xor(ps, 32, 64);
    size_t pbase = (size_t)(j * BATCH + b) * S;
    #pragma unroll
    for (int dt = 0; dt < 8; ++dt)
        #pragma unroll
        for (int r = 0; r < 4; ++r) {
            int row = m0 + w * 16 + quad * 4 + r;
            part[(pbase + row) * D + dt * 16 + col] = (_Float16)O[dt][r];
        }
    if (quad == 0) stats[pbase + m0 + w * 16 + col] = ps;

    // ---- last-finisher combine: 4th split-block of (b, mg) merges splits ----
    __syncthreads();  // drains all the block's global stores (vmcnt 0)
    if (tid == 0) {
        unsigned old = __hip_atomic_fetch_add(&done[b * 32 + mg], 1u,
                                              __ATOMIC_ACQ_REL,
                                              __HIP_MEMORY_SCOPE_AGENT);
        cflag = (old == NS - 1);
    }
    __syncthreads();
    if (!cflag) return;

    bool needMean = (Lb - m0) < 64;  // straddling group (block-uniform)
    if (needMean) {
        if (tid < 128) {
            float cs = 0.f;
            #pragma unroll 4
            for (int cc = 0; cc < 32; ++cc) cs += psums[(b * 32 + cc) * 128 + tid];
            cmean[tid] = cs * (1.0f / (float)S);
        }
        __syncthreads();
    }
    int r2 = tid >> 2, d0c = (tid & 3) * 32;
    int srow = m0 + r2;
    float* orow = out + ((size_t)b * S + srow) * D + d0c;
    if (srow >= Lb) {
        #pragma unroll
        for (int sg = 0; sg < 8; ++sg)
            *(f4*)(orow + sg * 4) = *(const f4*)&cmean[d0c + sg * 4];
    } else {
        float l = 0.f;
        #pragma unroll
        for (int jj = 0; jj < NS; ++jj)
            l += stats[(size_t)(jj * BATCH + b) * S + srow];
        float inv = 1.0f / l;
        f4 o[8];
        #pragma unroll
        for (int i = 0; i < 8; ++i) o[i] = (f4){0.f, 0.f, 0.f, 0.f};
        #pragma unroll
        for (int jj = 0; jj < NS; ++jj) {
            const half8* p = (const half8*)(part + ((size_t)(jj * BATCH + b) * S + srow) * D + d0c);
            #pragma unroll
            for (int sg = 0; sg < 4; ++sg) {
                half8 h = p[sg];
                f4 x0 = {(float)h[0], (float)h[1], (float)h[2], (float)h[3]};
                f4 x1 = {(float)h[4], (float)h[5], (float)h[6], (float)h[7]};
                o[sg * 2] += x0;
                o[sg * 2 + 1] += x1;
            }
        }
        #pragma unroll
        for (int i = 0; i < 8; ++i) *(f4*)(orow + i * 4) = o[i] * inv;
    }
}

extern "C" void kernel_launch(void* const* d_in, const int* in_sizes, int n_in,
                              void* d_out, int out_size, void* d_ws, size_t ws_size,
                              hipStream_t stream) {
    const float* q = (const float*)d_in[0];
    const float* k = (const float*)d_in[1];
    const float* v = (const float*)d_in[2];
    const int* el = (const int*)d_in[3];
    float* out = (float*)d_out;

    // ws layout: done(1KB) | psums(128KB) | kh | vt | stats | part
    const size_t SZ_DONE = 1024;
    const size_t SZ_PS = (size_t)BATCH * 32 * 128 * 4;    // 128 KB
    const size_t SZ_HALF = (size_t)BATCH * D * S * 2;     // 4.19 MB each
    const size_t SZ_STAT = (size_t)NS * BATCH * S * 4;    // 256 KB
    unsigned* done = (unsigned*)d_ws;
    float* psums = (float*)((char*)d_ws + SZ_DONE);
    _Float16* kh = (_Float16*)((char*)d_ws + SZ_DONE + SZ_PS);
    _Float16* vt = (_Float16*)((char*)d_ws + SZ_DONE + SZ_PS + SZ_HALF);
    float* stats = (float*)((char*)d_ws + SZ_DONE + SZ_PS + 2 * SZ_HALF);
    _Float16* part = (_Float16*)((char*)d_ws + SZ_DONE + SZ_PS + 2 * SZ_HALF + SZ_STAT);

    k_prep<<<dim3(32, 8), 256, 0, stream>>>(k, v, kh, vt, psums, done);
    k_attn<<<dim3(1024), 256, 0, stream>>>(q, kh, vt, el, psums, part, stats,
                                           done, out);
}